// Round 7
// baseline (934.452 us; speedup 1.0000x reference)
//
#include <hip/hip_runtime.h>
#include <hip/hip_bf16.h>
#include <stdint.h>

// ConvIntrinsic: fused  out[k,o,t] = relu( Σ_f sw[t,f]·ms[k,f]
//                + Σ_{x,y,f} W3[o,t,x,y,f]·interp0[k,x,y,f] + bias[t] )
// => GEMM (K=100000 × 1312) @ (1312 × 768), o=8 column duplicates o=0.
//
// R6: occupancy re-tiling, rebuilt from validated parts only (R5's novel
// rewrite failed correctness). BM=32, 512 threads / 8 waves (2m x 4n),
// acc[12] = 48 regs, __launch_bounds__(512,4) -> <=128 regs -> 4 waves/SIMD
// = 2 blocks/CU (vs 1 before): cross-block TLP covers the per-barrier
// vmcnt-drain windows (m114 mechanism). A-build lambdas verbatim from R4
// (float4 gathers, short4v commit, 256 builder threads); pipeline structure
// verbatim from R1 (issue-top / commit-bottom, plain __syncthreads).

typedef __attribute__((ext_vector_type(8))) short short8;
typedef __attribute__((ext_vector_type(4))) short short4v;
typedef __attribute__((ext_vector_type(4))) float floatx4;
typedef __attribute__((ext_vector_type(2))) float fx2;

#define KPTS 100000
#define OUT_STRIDE 864   // 9*96
#define BM 32
#define THREADS 512

__device__ __forceinline__ short f2bf(float x) {
  union { float f; uint32_t u; } c; c.f = x;
  uint32_t u = c.u;
  u += 0x7FFFu + ((u >> 16) & 1u);   // round-to-nearest-even
  return (short)(u >> 16);
}

// ---------------- prep: pack B in MFMA fragment layout --------------------
// Bp[ch][ntile][lane][j] = B[c = ch*32 + (lane>>4)*8 + j][n = ntile*16 + (lane&15)]
__global__ void prep_B(const float* __restrict__ kern,
                       const float* __restrict__ tw,
                       const float* __restrict__ sw,
                       short* __restrict__ Bp) {
  const int ntile = blockIdx.x;   // 0..47
  const int ch    = blockIdx.y;   // 0..40
  const int lane  = threadIdx.x;  // 0..63
  const int n = ntile * 16 + (lane & 15);
  const int o = n / 96;
  const int t = n - o * 96;
  const int fb = (lane >> 4) * 8;

  short8 v;
  if (ch < 40) {
    float kcol[40];
#pragma unroll
    for (int ra = 0; ra < 40; ++ra) kcol[ra] = kern[ra * 40 + ch];
#pragma unroll
    for (int j = 0; j < 8; ++j) {
      const int f = fb + j;
      float acc = 0.f;
      for (int r = 0; r < 5; ++r) {
#pragma unroll
        for (int a = 0; a < 8; ++a) {
          acc += kcol[r * 8 + a] * tw[((t * 5 + r) * 8 + ((a + o) & 7)) * 32 + f];
        }
      }
      v[j] = f2bf(acc);
    }
  } else {
#pragma unroll
    for (int j = 0; j < 8; ++j) v[j] = f2bf(sw[t * 32 + fb + j]);
  }
  *reinterpret_cast<short8*>(Bp + ((size_t)(ch * 48 + ntile) * 64 + lane) * 8) = v;
}

// ---------------- main fused GEMM ----------------------------------------
__global__ __launch_bounds__(THREADS, 4) void conv_main(
    const float* __restrict__ ms,
    const float* __restrict__ bary,
    const float* __restrict__ bias,
    const short* __restrict__ Bp,
    float* __restrict__ out) {
  __shared__ short Atile[2][BM][40];   // row stride 80 B; cols 32..39 unused pad

  const int kbase = blockIdx.x * BM;   // 3125 blocks, no tail (100000 = 3125*32)
  const int tid = threadIdx.x;
  const int lane = tid & 63;
  const int wid = tid >> 6;            // 0..7
  const int wm = wid >> 2;             // 0..1  (m-half: rows wm*16)
  const int wn = wid & 3;              // 0..3  (n-group: cols wn*192)
  const int l15 = lane & 15;
  const int kh = lane >> 4;            // 0..3

  // A-build role (R4-verbatim): 8 threads per row, 4 f-columns each.
  // 32 rows x 8 = 256 builder threads; waves 4..7 idle in build phases.
  const bool builder = tid < 256;
  const int arow = tid >> 3;           // 0..31 (only meaningful for builders)
  const int af0 = (tid & 7) * 4;       // 0,4,...,28
  const int krow = kbase + (arow & 31);
  const float* __restrict__ brow = bary + (size_t)krow * 240;
  const float* __restrict__ mrow = ms + (size_t)krow * 32 + af0;

  fx2 q0, q1, q2;                      // bary for next chunk (one ahead)
  floatx4 GA, GB, GC;                  // gathers in flight
  float W0, W1, W2;

  auto ldbary = [&](int c) {
    const fx2* bp = (const fx2*)(brow + c * 6);
    q0 = __builtin_nontemporal_load(bp);
    q1 = __builtin_nontemporal_load(bp + 1);
    q2 = __builtin_nontemporal_load(bp + 2);
  };
  auto issueG = [&](int c) {
    if (c == 40) {                     // center chunk: A[k][1280+f] = ms[k][f]
      GA = *(const floatx4*)(mrow);
      GB = (floatx4)0.f; GC = (floatx4)0.f;
      W0 = 1.f; W1 = 0.f; W2 = 0.f;
    } else {
      GA = *(const floatx4*)(ms + ((size_t)(int)q0.x) * 32 + af0);
      GB = *(const floatx4*)(ms + ((size_t)(int)q1.x) * 32 + af0);
      GC = *(const floatx4*)(ms + ((size_t)(int)q2.x) * 32 + af0);
      W0 = q0.y; W1 = q1.y; W2 = q2.y;
    }
  };
  auto commitG = [&](int buf) {
    short4v s;
    s[0] = f2bf(W0 * GA[0] + W1 * GB[0] + W2 * GC[0]);
    s[1] = f2bf(W0 * GA[1] + W1 * GB[1] + W2 * GC[1]);
    s[2] = f2bf(W0 * GA[2] + W1 * GB[2] + W2 * GC[2]);
    s[3] = f2bf(W0 * GA[3] + W1 * GB[3] + W2 * GC[3]);
    *reinterpret_cast<short4v*>(&Atile[buf][arow][af0]) = s;
  };

  floatx4 acc[12];
#pragma unroll
  for (int j = 0; j < 12; ++j) acc[j] = (floatx4)0.f;

  // ---- prologue: build chunk 0 (one exposed stall, once) ----
  if (builder) {
    ldbary(0);
    issueG(0);
    commitG(0);
    ldbary(1);                         // q = bary(1) for iter 0
  }
  __syncthreads();

  for (int ch = 0; ch <= 40; ++ch) {
    const int cur = ch & 1;
    if (builder) {
      if (ch < 40) issueG(ch + 1);     // gathers -> regs (addresses from q)
      if (ch < 38) ldbary(ch + 2);     // refill q; last needed chunk is 39
    }

    short8 af = *reinterpret_cast<const short8*>(&Atile[cur][wm * 16 + l15][kh * 8]);
    const short* bb = Bp + ((size_t)(ch * 48 + wn * 12) * 64 + lane) * 8;
#pragma unroll
    for (int nj = 0; nj < 12; ++nj) {
      short8 bf = *reinterpret_cast<const short8*>(bb + (size_t)nj * 512);
      acc[nj] = __builtin_amdgcn_mfma_f32_16x16x32_bf16(af, bf, acc[nj], 0, 0, 0);
    }

    if (builder && ch < 40) commitG(cur ^ 1);  // interp + ds_write next buf
    __syncthreads();
  }

  // epilogue: bias + relu; out[k,o,t] = out[k*864 + n]; o=8 duplicates o=0
#pragma unroll
  for (int nj = 0; nj < 12; ++nj) {
    const int n = wn * 192 + nj * 16 + l15;          // wn*192 ≡ 0 (mod 96)
    const float bsv = bias[(nj % 6) * 16 + l15];     // = bias[n % 96]
    const bool dup = (wn == 0) && (nj < 6);          // n < 96
#pragma unroll
    for (int i = 0; i < 4; ++i) {
      const int r = kbase + wm * 16 + kh * 4 + i;
      float vv = fmaxf(acc[nj][i] + bsv, 0.f);
      out[(size_t)r * OUT_STRIDE + n] = vv;
      if (dup) out[(size_t)r * OUT_STRIDE + 768 + n] = vv;
    }
  }
}

extern "C" void kernel_launch(void* const* d_in, const int* in_sizes, int n_in,
                              void* d_out, int out_size, void* d_ws, size_t ws_size,
                              hipStream_t stream) {
  const float* ms   = (const float*)d_in[0];  // (K,32)
  const float* bary = (const float*)d_in[1];  // (K,5,8,3,2)
  const float* kern = (const float*)d_in[2];  // (5,8,5,8)
  const float* tw   = (const float*)d_in[3];  // (96,5,8,32)
  const float* sw   = (const float*)d_in[4];  // (96,1,32)
  const float* bias = (const float*)d_in[5];  // (96,)
  float* out = (float*)d_out;
  short* Bp = (short*)d_ws;                   // 41*48*64*8 bf16 ≈ 2.02 MB

  hipLaunchKernelGGL(prep_B, dim3(48, 41), dim3(64), 0, stream, kern, tw, sw, Bp);
  hipLaunchKernelGGL(conv_main, dim3(3125), dim3(THREADS), 0, stream,
                     ms, bary, bias, Bp, out);
}

// Round 8
// 454.864 us; speedup vs baseline: 2.0544x; 2.0544x over previous
//
#include <hip/hip_runtime.h>
#include <hip/hip_bf16.h>
#include <stdint.h>

// ConvIntrinsic: fused  out[k,o,t] = relu( Σ_f sw[t,f]·ms[k,f]
//                + Σ_{x,y,f} W3[o,t,x,y,f]·interp0[k,x,y,f] + bias[t] )
// => GEMM (K=100000 × 1312) @ (1312 × 768), o=8 column duplicates o=0.
//
// R7: R3 structure verbatim (BM=64, 8 waves 64x96, 2-ahead gathers,
// issue-top/commit-bottom) with ONE variable changed: the barrier.
//   R3: asm("s_waitcnt lgkmcnt(0); s_barrier" ::: "memory")  -> clobber made
//       SIInsertWaitcnts drain vmcnt(0) anyway (null result).
//   R4: dropped clobber but added 3x sched_barrier pins + setprio -> m141
//       over-pinning regression.
//   R7: sched_barrier(0) [pins ds_write above] + bare lgkmcnt asm (no
//       clobber) + s_barrier intrinsic. Global loads (gathers/bary/B) now
//       stay in flight across barriers; compiler-counted vmcnt at use.
// R6 lesson encoded: per-CU VMEM bytes are the co-binding resource
// (~22 B/cy/CU effective); BM=64 keeps B at 48 KB/CU/chunk (minimal).

typedef __attribute__((ext_vector_type(8))) short short8;
typedef __attribute__((ext_vector_type(4))) short short4v;
typedef __attribute__((ext_vector_type(4))) float floatx4;
typedef __attribute__((ext_vector_type(2))) float fx2;

#define KPTS 100000
#define OUT_STRIDE 864   // 9*96
#define BM 64
#define THREADS 512

// Workgroup barrier that does NOT drain vmcnt:
//  - sched_barrier(0): nothing from above (esp. the commit ds_write) sinks below
//  - bare lgkmcnt(0): waits the ds_write; no "memory" clobber -> no vmcnt drain
//  - s_barrier intrinsic: memory ops can't be scheduled across it (side effects)
#define BARRIER() do {                              \
    __builtin_amdgcn_sched_barrier(0);              \
    asm volatile("s_waitcnt lgkmcnt(0)");           \
    __builtin_amdgcn_s_barrier();                   \
  } while (0)

__device__ __forceinline__ short f2bf(float x) {
  union { float f; uint32_t u; } c; c.f = x;
  uint32_t u = c.u;
  u += 0x7FFFu + ((u >> 16) & 1u);   // round-to-nearest-even
  return (short)(u >> 16);
}

// ---------------- prep: pack B in MFMA fragment layout --------------------
// Bp[ch][ntile][lane][j] = B[c = ch*32 + (lane>>4)*8 + j][n = ntile*16 + (lane&15)]
__global__ void prep_B(const float* __restrict__ kern,
                       const float* __restrict__ tw,
                       const float* __restrict__ sw,
                       short* __restrict__ Bp) {
  const int ntile = blockIdx.x;   // 0..47
  const int ch    = blockIdx.y;   // 0..40
  const int lane  = threadIdx.x;  // 0..63
  const int n = ntile * 16 + (lane & 15);
  const int o = n / 96;
  const int t = n - o * 96;
  const int fb = (lane >> 4) * 8;

  short8 v;
  if (ch < 40) {
    float kcol[40];
#pragma unroll
    for (int ra = 0; ra < 40; ++ra) kcol[ra] = kern[ra * 40 + ch];
#pragma unroll
    for (int j = 0; j < 8; ++j) {
      const int f = fb + j;
      float acc = 0.f;
      for (int r = 0; r < 5; ++r) {
#pragma unroll
        for (int a = 0; a < 8; ++a) {
          acc += kcol[r * 8 + a] * tw[((t * 5 + r) * 8 + ((a + o) & 7)) * 32 + f];
        }
      }
      v[j] = f2bf(acc);
    }
  } else {
#pragma unroll
    for (int j = 0; j < 8; ++j) v[j] = f2bf(sw[t * 32 + fb + j]);
  }
  *reinterpret_cast<short8*>(Bp + ((size_t)(ch * 48 + ntile) * 64 + lane) * 8) = v;
}

// ---------------- main fused GEMM ----------------------------------------
__global__ __launch_bounds__(THREADS, 1) void conv_main(
    const float* __restrict__ ms,
    const float* __restrict__ bary,
    const float* __restrict__ bias,
    const short* __restrict__ Bp,
    float* __restrict__ out) {
  __shared__ short Atile[2][BM][40];   // stride 40 shorts: conflict-free

  const int kbase = blockIdx.x * BM;
  const int tid = threadIdx.x;
  const int lane = tid & 63;
  const int wn = tid >> 6;             // 0..7  (wave n-group: cols wn*96)
  const int l15 = lane & 15;
  const int kh = lane >> 4;            // 0..3

  // A-build role: 8 threads per row, 4 f-columns each
  const int arow = tid >> 3;           // 0..63
  const int af0 = (tid & 7) * 4;       // 0,4,...,28
  const int krow = kbase + arow;
  const bool rowok = krow < KPTS;
  const float* __restrict__ brow = bary + (size_t)(rowok ? krow : 0) * 240;

  // bary register sets (chunk parity): loaded 1 iter before use
  fx2 bE0, bE1, bE2, bO0, bO1, bO2;
  // gather register sets (chunk parity): issued 1 full iter before commit
  floatx4 eG0, eG1, eG2, oG0, oG1, oG2;
  float eW0, eW1, eW2, oW0, oW1, oW2;

  auto ldbary = [&](int c, fx2& p0, fx2& p1, fx2& p2) {
    if (rowok) {
      const fx2* bp = (const fx2*)(brow + c * 6);
      p0 = __builtin_nontemporal_load(bp);
      p1 = __builtin_nontemporal_load(bp + 1);
      p2 = __builtin_nontemporal_load(bp + 2);
    } else {
      p0 = (fx2)0.f; p1 = (fx2)0.f; p2 = (fx2)0.f;
    }
  };
  auto issueG = [&](int c, const fx2& p0, const fx2& p1, const fx2& p2,
                    floatx4& A, floatx4& B, floatx4& C,
                    float& W0, float& W1, float& W2) {
    if (c == 40) {   // center chunk: A[k][1280+f] = ms[k][f]
      A = *(const floatx4*)(ms + (size_t)(rowok ? krow : 0) * 32 + af0);
      B = (floatx4)0.f; C = (floatx4)0.f;
      W0 = rowok ? 1.f : 0.f; W1 = 0.f; W2 = 0.f;
    } else {
      A = *(const floatx4*)(ms + ((size_t)(int)p0.x) * 32 + af0);
      B = *(const floatx4*)(ms + ((size_t)(int)p1.x) * 32 + af0);
      C = *(const floatx4*)(ms + ((size_t)(int)p2.x) * 32 + af0);
      W0 = p0.y; W1 = p1.y; W2 = p2.y;
    }
  };
  auto commitG = [&](const floatx4& A, const floatx4& B, const floatx4& C,
                     float W0, float W1, float W2, int buf) {
    short4v s;
    s[0] = f2bf(W0 * A[0] + W1 * B[0] + W2 * C[0]);
    s[1] = f2bf(W0 * A[1] + W1 * B[1] + W2 * C[1]);
    s[2] = f2bf(W0 * A[2] + W1 * B[2] + W2 * C[2]);
    s[3] = f2bf(W0 * A[3] + W1 * B[3] + W2 * C[3]);
    *reinterpret_cast<short4v*>(&Atile[buf][arow][af0]) = s;
  };

  short8 bfA[6], bfB[6];
  auto loadB = [&](int c, short8* dst) {
    const short* bp = Bp + ((size_t)(c * 48 + wn * 6) * 64 + lane) * 8;
#pragma unroll
    for (int j = 0; j < 6; ++j)
      dst[j] = *reinterpret_cast<const short8*>(bp + (size_t)j * 512);
  };

  floatx4 acc[4][6];
#pragma unroll
  for (int mi = 0; mi < 4; ++mi)
#pragma unroll
    for (int nj = 0; nj < 6; ++nj) acc[mi][nj] = (floatx4)0.f;

  // ---- prologue ----
  {
    fx2 t0, t1, t2;
    ldbary(0, t0, t1, t2);
    issueG(0, t0, t1, t2, eG0, eG1, eG2, eW0, eW1, eW2);
    ldbary(1, t0, t1, t2);
    issueG(1, t0, t1, t2, oG0, oG1, oG2, oW0, oW1, oW2);
  }
  ldbary(2, bE0, bE1, bE2);           // for issue(2) at iter 0
  commitG(eG0, eG1, eG2, eW0, eW1, eW2, 0);   // chunk 0 -> Atile[0]
  loadB(0, bfA);
  BARRIER();

  // iter ch: issue(ch+2) with bary set (ch&1); ldbary(ch+3) -> other set;
  // MFMA chunk ch from Atile[ch&1] with B-set BF; loadB(ch+1) -> NBF;
  // commit(ch+1) -> Atile[(ch&1)^1]; barrier (global loads stay in flight).
#define ITER(ch, UB0, UB1, UB2, FB0, FB1, FB2,                                  \
             FG0, FG1, FG2, FW0, FW1, FW2,                                      \
             CG0, CG1, CG2, CW0, CW1, CW2, CUR, BF, NBF)                        \
  {                                                                             \
    if ((ch) + 2 <= 40)                                                         \
      issueG((ch) + 2, UB0, UB1, UB2, FG0, FG1, FG2, FW0, FW1, FW2);            \
    if ((ch) + 3 <= 39) ldbary((ch) + 3, FB0, FB1, FB2);                        \
    short8 af[4];                                                               \
    _Pragma("unroll")                                                           \
    for (int mi = 0; mi < 4; ++mi)                                              \
      af[mi] = *reinterpret_cast<const short8*>(&Atile[CUR][mi * 16 + l15][kh * 8]); \
    if ((ch) + 1 <= 40) loadB((ch) + 1, NBF);                                   \
    _Pragma("unroll")                                                           \
    for (int nj = 0; nj < 6; ++nj)                                              \
      _Pragma("unroll")                                                         \
      for (int mi = 0; mi < 4; ++mi)                                            \
        acc[mi][nj] = __builtin_amdgcn_mfma_f32_16x16x32_bf16(af[mi], BF[nj],   \
                                                              acc[mi][nj], 0, 0, 0); \
    if ((ch) + 1 <= 40)                                                         \
      commitG(CG0, CG1, CG2, CW0, CW1, CW2, (CUR) ^ 1);                         \
    BARRIER();                                                                  \
  }

  for (int ch = 0; ch < 40; ch += 2) {
    // even iter: use bE, fill bO; fill E gathers, commit O gathers; Atile[0]; B=bfA
    ITER(ch,     bE0, bE1, bE2, bO0, bO1, bO2,
         eG0, eG1, eG2, eW0, eW1, eW2,
         oG0, oG1, oG2, oW0, oW1, oW2, 0, bfA, bfB)
    // odd iter: use bO, fill bE; fill O gathers, commit E gathers; Atile[1]; B=bfB
    ITER(ch + 1, bO0, bO1, bO2, bE0, bE1, bE2,
         oG0, oG1, oG2, oW0, oW1, oW2,
         eG0, eG1, eG2, eW0, eW1, eW2, 1, bfB, bfA)
  }
  ITER(40, bE0, bE1, bE2, bO0, bO1, bO2,
       eG0, eG1, eG2, eW0, eW1, eW2,
       oG0, oG1, oG2, oW0, oW1, oW2, 0, bfA, bfB)
#undef ITER

  // epilogue: bias + relu; out[k,o,t] = out[k*864 + n]; o=8 duplicates o=0
#pragma unroll
  for (int mi = 0; mi < 4; ++mi) {
    const int rb = kbase + mi * 16 + kh * 4;
#pragma unroll
    for (int nj = 0; nj < 6; ++nj) {
      const int n = wn * 96 + nj * 16 + l15;
      const float bsv = bias[nj * 16 + l15];
      const bool dup = (wn == 0);
#pragma unroll
      for (int i = 0; i < 4; ++i) {
        const int r = rb + i;
        if (r < KPTS) {
          float vv = fmaxf(acc[mi][nj][i] + bsv, 0.f);
          out[(size_t)r * OUT_STRIDE + n] = vv;
          if (dup) out[(size_t)r * OUT_STRIDE + 768 + n] = vv;
        }
      }
    }
  }
}

extern "C" void kernel_launch(void* const* d_in, const int* in_sizes, int n_in,
                              void* d_out, int out_size, void* d_ws, size_t ws_size,
                              hipStream_t stream) {
  const float* ms   = (const float*)d_in[0];  // (K,32)
  const float* bary = (const float*)d_in[1];  // (K,5,8,3,2)
  const float* kern = (const float*)d_in[2];  // (5,8,5,8)
  const float* tw   = (const float*)d_in[3];  // (96,5,8,32)
  const float* sw   = (const float*)d_in[4];  // (96,1,32)
  const float* bias = (const float*)d_in[5];  // (96,)
  float* out = (float*)d_out;
  short* Bp = (short*)d_ws;                   // 41*48*64*8 bf16 ≈ 2.02 MB

  hipLaunchKernelGGL(prep_B, dim3(48, 41), dim3(64), 0, stream, kern, tw, sw, Bp);
  hipLaunchKernelGGL(conv_main, dim3(1563), dim3(THREADS), 0, stream,
                     ms, bary, bias, Bp, out);
}